// Round 23
// baseline (286.438 us; speedup 1.0000x reference)
//
#include <hip/hip_runtime.h>
#include <hip/hip_bf16.h>
#include <stdint.h>

// Problem constants (from reference)
#define M_TOTAL 131072
#define K_DIM   512
#define N_RANK  256
#define NSEG    1024
#define KC      64              // k-chunk (64 f32 per row) held in registers
#define NKC     (K_DIM / KC)    // 8
#define BM      64              // rows per block (4 waves x 16 rows)
#define NBLK    (M_TOTAL / BM)  // 2048 fused blocks
#define NB16    (M_TOTAL / 16)  // 8192 16-row groups (pass2 granularity)

typedef __attribute__((ext_vector_type(8))) short bf16x8;
typedef __attribute__((ext_vector_type(4))) float f32x4;

__device__ inline short f2b(float f) {
    __hip_bfloat16 h = __float2bfloat16(f);
    return __builtin_bit_cast(short, h);
}

// fast tanh: t = sign(z) * (1 - 2/(e^{2|z|}+1))
__device__ inline float fast_tanh(float z) {
    float e = __expf(2.0f * fabsf(z));
    return copysignf(1.0f - 2.0f / (e + 1.0f), z);
}

// Kernel 1: init out to 1.0 (segment_prod identity for empty segments)
//           + convert W to bf16 in ws
__global__ void prep_kernel(const float* __restrict__ W,
                            __hip_bfloat16* __restrict__ Wb,
                            float* __restrict__ out) {
    int i = blockIdx.x * 256 + threadIdx.x;
    out[i] = 1.0f;
    if (i < N_RANK * K_DIM) Wb[i] = __float2bfloat16(W[i]);
}

// Kernel 2 (pass 1): fused GEMM + bias + tanh + in-register segmented product.
//
// R23: ZERO-LDS / ZERO-BARRIER structure. Each wave independently owns
// 16 rows x 256 cols. MFMA A-fragments load DIRECTLY from global:
// lane (g,l16) reads x[row0+l16][kc*64+s*32+g*8] (8 contiguous f32) --
// exactly the 16x16x32 A-layout, no shuffles, no staging, cvt once
// (the R12-family's 8x cvt/LDS-read amplification is gone). B streams
// from L2/L1 (W chunk = 32 KB ~ L1-resident; shared chip-wide). All
// latency hiding via TLP: 16 fully independent waves/CU, no convoying.
// Regs: acc 64 + sg 16 + av 8 + b 8 + addr ~116 (proven-safe shape).
//
// History: R12-family (LDS col-slice, barrier-phased) plateaued at 78-81us
// with no pipe >55% -- the residual was block-wide convoying. This is the
// orthogonal escape: remove the coupling entirely.
__launch_bounds__(256, 4)   // reg cap 128; spill canary = WRITE_SIZE balloon
__global__ void fused_kernel(const float* __restrict__ x,
                             const __hip_bfloat16* __restrict__ Wb,
                             const float* __restrict__ bias,
                             const int* __restrict__ seg,
                             float* __restrict__ out,
                             float* __restrict__ partial) {
    const int tid  = threadIdx.x;
    const int wave = tid >> 6;        // 0..3
    const int lane = tid & 63;
    const int l16  = lane & 15;
    const int g    = lane >> 4;       // 0..3 (k-group)
    const int bid  = blockIdx.x;
    const int row0 = bid * BM + wave * 16;   // wave's rows: row0 + l16
    const int grp  = bid * 4 + wave;         // 16-row group id

    f32x4 acc[16] = {};               // acc[n] = 16x16 tile for cols n*16..+15
    f32x4 sg[4];                      // A f32 for current chunk (2 s x 2 halves)
    bf16x8 av[2];                     // A bf16 fragments (s=0,1)

    // lane's A base: row row0+l16, col offset g*8
    const float* xrow = x + (size_t)(row0 + l16) * K_DIM + g * 8;
    const __hip_bfloat16* wbase = Wb + (size_t)l16 * K_DIM + g * 8;

    #define A_LOAD(kc_)                                                       \
        do {                                                                  \
            _Pragma("unroll")                                                 \
            for (int s = 0; s < 2; ++s)                                       \
                _Pragma("unroll")                                             \
                for (int h2 = 0; h2 < 2; ++h2)                                \
                    sg[s * 2 + h2] = *reinterpret_cast<const f32x4*>(         \
                        xrow + (kc_) * KC + s * 32 + h2 * 4);                 \
        } while (0)

    // ---- prologue: load chunk 0's A ----
    A_LOAD(0);

    // ---- K loop: 8 chunks, no barriers, no LDS ----
    #pragma unroll
    for (int kc = 0; kc < NKC; ++kc) {
        // cvt A (compiler waits on sg loads); VALU reads at issue -> safe to
        // reuse sg for the next chunk's loads right after
        #pragma unroll
        for (int s = 0; s < 2; ++s) {
            bf16x8 a;
            a[0] = f2b(sg[s * 2][0]);     a[1] = f2b(sg[s * 2][1]);
            a[2] = f2b(sg[s * 2][2]);     a[3] = f2b(sg[s * 2][3]);
            a[4] = f2b(sg[s * 2 + 1][0]); a[5] = f2b(sg[s * 2 + 1][1]);
            a[6] = f2b(sg[s * 2 + 1][2]); a[7] = f2b(sg[s * 2 + 1][3]);
            av[s] = a;
        }
        // prefetch next chunk's A (oldest-vs-B ordering irrelevant: B waits
        // retire these too, and they have 32 loads + 32 MFMAs of cover)
        if (kc + 1 < NKC) A_LOAD(kc + 1);

        // 16 n-tiles: 2 B-loads + 2 MFMA each; L1/L2-resident W
        #pragma unroll
        for (int n = 0; n < 16; ++n) {
            const __hip_bfloat16* wp = wbase + (size_t)(n * 16) * K_DIM + kc * KC;
            bf16x8 b0 = *reinterpret_cast<const bf16x8*>(wp);
            bf16x8 b1 = *reinterpret_cast<const bf16x8*>(wp + 32);
            acc[n] = __builtin_amdgcn_mfma_f32_16x16x32_bf16(av[0], b0, acc[n], 0, 0, 0);
            acc[n] = __builtin_amdgcn_mfma_f32_16x16x32_bf16(av[1], b1, acc[n], 0, 0, 0);
        }
    }
    #undef A_LOAD

    // ---- bias + tanh in regs ----
    // D layout: col = lane&15 (of tile n), row(within 16) = g*4 + r
    #pragma unroll
    for (int n = 0; n < 16; ++n) {
        const float bj = bias[n * 16 + l16];
        #pragma unroll
        for (int r = 0; r < 4; ++r)
            acc[n][r] = fast_tanh(acc[n][r] + bj);
    }

    // ---- in-register segmented product over the wave's 16 rows ----
    const int myseg  = seg[row0 + l16];
    const int prevsg = (l16 == 0) ? (myseg ^ 1) : seg[row0 + l16 - 1];
    uint32_t m = (uint32_t)__ballot(myseg != prevsg) & 0xFFFFu;  // low 16 lanes

    while (m) {
        const int start = (int)__builtin_ctz(m);
        m &= m - 1;
        const int end = m ? (int)__builtin_ctz(m) : 16;
        const int s   = __shfl(myseg, start);        // run's segment id

        float p[16];
        #pragma unroll
        for (int n = 0; n < 16; ++n) p[n] = 1.0f;
        #pragma unroll
        for (int r = 0; r < 4; ++r) {
            const int row = g * 4 + r;
            const bool in = (row >= start) && (row < end);
            #pragma unroll
            for (int n = 0; n < 16; ++n)
                p[n] *= in ? acc[n][r] : 1.0f;
        }
        #pragma unroll
        for (int n = 0; n < 16; ++n) {
            p[n] *= __shfl_xor(p[n], 16);
            p[n] *= __shfl_xor(p[n], 32);
        }
        if (g == 0) {
            #pragma unroll
            for (int n = 0; n < 16; ++n) {
                const int col = n * 16 + l16;
                if (start == 0)
                    partial[(size_t)(grp * 2 + 0) * N_RANK + col] = p[n];
                else if (end == 16)
                    partial[(size_t)(grp * 2 + 1) * N_RANK + col] = p[n];
                else
                    out[(size_t)s * N_RANK + col] = p[n];    // interior: exclusive
            }
        }
    }
}

// Kernel 3 (pass 2): combine boundary partials over 16-row groups (b = grp).
// Group b owns boundary segment s iff s first appears in group b. Interior
// segments were stored by pass 1; empty segments stay 1.0.
__global__ void pass2_kernel(const int* __restrict__ seg,
                             const float* __restrict__ partial,
                             float* __restrict__ out) {
    const int b   = blockIdx.x;
    const int col = threadIdx.x;      // 0..255
    const int sF    = seg[b * 16];
    const int sL    = seg[b * 16 + 15];
    const int prevL = (b == 0) ? -1 : seg[b * 16 - 1];

    if (prevL < sF) {                 // b owns its first segment
        float p = partial[(size_t)(b * 2 + 0) * N_RANK + col];
        for (int b2 = b + 1; b2 < NB16 && seg[b2 * 16] == sF; ++b2)
            p *= partial[(size_t)(b2 * 2 + 0) * N_RANK + col];
        out[(size_t)sF * N_RANK + col] = p;
    }
    if (sL != sF) {                   // b always owns sL when sL != sF
        float p = partial[(size_t)(b * 2 + 1) * N_RANK + col];
        for (int b2 = b + 1; b2 < NB16 && seg[b2 * 16] == sL; ++b2)
            p *= partial[(size_t)(b2 * 2 + 0) * N_RANK + col];
        out[(size_t)sL * N_RANK + col] = p;
    }
}

extern "C" void kernel_launch(void* const* d_in, const int* in_sizes, int n_in,
                              void* d_out, int out_size, void* d_ws, size_t ws_size,
                              hipStream_t stream) {
    const float* x   = (const float*)d_in[0];
    const float* W   = (const float*)d_in[1];
    const float* b   = (const float*)d_in[2];
    const int*   seg = (const int*)d_in[3];
    float*       out = (float*)d_out;
    __hip_bfloat16* Wb = (__hip_bfloat16*)d_ws;                 // 256 KB
    float* partial = (float*)((char*)d_ws + (1 << 20));         // ~16.8 MB @ +1MB

    prep_kernel<<<(NSEG * N_RANK) / 256, 256, 0, stream>>>(W, Wb, out);
    fused_kernel<<<NBLK, 256, 0, stream>>>(x, Wb, b, seg, out, partial);
    pass2_kernel<<<NB16, 256, 0, stream>>>(seg, partial, out);
}

// Round 24
// 78.305 us; speedup vs baseline: 3.6580x; 3.6580x over previous
//
#include <hip/hip_runtime.h>
#include <hip/hip_bf16.h>
#include <stdint.h>

// Problem constants (from reference)
#define M_TOTAL 131072
#define K_DIM   512
#define N_RANK  256
#define NSEG    1024
#define KC      64              // k-chunk staged in LDS (64 bf16 per row)
#define NKC     (K_DIM / KC)    // 8
#define BM      128             // rows per block
#define NBLK    (M_TOTAL / BM)  // 1024 fused blocks
#define NB64    (M_TOTAL / 64)  // 2048 virtual 64-row groups (pass2 granularity)

typedef __attribute__((ext_vector_type(8))) short bf16x8;
typedef __attribute__((ext_vector_type(4))) float f32x4;

// Raw barrier: lgkmcnt(0) makes my ds_writes visible, vmcnt NOT drained.
#define BAR() do { \
    asm volatile("s_waitcnt lgkmcnt(0)" ::: "memory"); \
    __builtin_amdgcn_s_barrier(); \
} while (0)

__device__ inline short f2b(float f) {
    __hip_bfloat16 h = __float2bfloat16(f);
    return __builtin_bit_cast(short, h);
}

// fast tanh: t = sign(z) * (1 - 2/(e^{2|z|}+1))
__device__ inline float fast_tanh(float z) {
    float e = __expf(2.0f * fabsf(z));
    return copysignf(1.0f - 2.0f / (e + 1.0f), z);
}

// Kernel 1: init out to 1.0 (segment_prod identity for empty segments)
//           + convert W to bf16 in ws
__global__ void prep_kernel(const float* __restrict__ W,
                            __hip_bfloat16* __restrict__ Wb,
                            float* __restrict__ out) {
    int i = blockIdx.x * 256 + threadIdx.x;
    out[i] = 1.0f;
    if (i < N_RANK * K_DIM) Wb[i] = __float2bfloat16(W[i]);
}

// Kernel 2 (pass 1): fused GEMM + bias + tanh + in-register segmented product.
//
// R24 = R22 verbatim (best measured: 78.1 us). R23's zero-LDS structure
// spilled (acc[16]+32 live B-loads >> 128-reg cap; VGPR=64, 286us) -- 4th
// confirmation that only this register shape fits the (512,4) cap.
//
// Final structure (measured over R1-R23):
//  - 8-wave col-slice, BM=128, KC=64: uniquely fits the 128-reg cap.
//  - TWO chunks per barrier via 4-deep LDS rotation (R22 -3us vs R19):
//    barriers 8->4; writes separated from conflicting reads by double
//    barriers (iteration j writes buffers computed-from in iteration j-1).
//  - bf16 converted ONCE at stage-write (R12 -7.4us).
//  - Single-barrier chunk schedule (R11 -6.7us); B-loads oldest in VMEM
//    queue -> counted B-use wait; G-loads newest -> fly over compute (R9).
//  - setprio around MFMA kept (R19, free). De-phasing hurts L2 (R20).
//  - Epilogue: in-register segmented product via ballot-run-walk + shfl_xor
//    (R8); no atomics (two-pass partial combine, R7).
__launch_bounds__(512, 4)   // reg cap 128; spill canary = WRITE_SIZE balloon
__global__ void fused_kernel(const float* __restrict__ x,
                             const __hip_bfloat16* __restrict__ Wb,
                             const float* __restrict__ bias,
                             const int* __restrict__ seg,
                             float* __restrict__ out,
                             float* __restrict__ partial) {
    const int tid  = threadIdx.x;
    const int wave = tid >> 6;        // 0..7 = column-slice
    const int lane = tid & 63;
    const int l16  = lane & 15;
    const int g    = lane >> 4;       // 0..3 (k-group / row-group)
    const int bid  = blockIdx.x;
    const int m0   = bid * BM;
    const int n0   = wave * 32;

    // LDS: A quad-buffer, 4 x (128 rows x 128B bf16) = 64 KB.
    __shared__ alignas(16) char smem[65536];

    // ---- staging geometry: thread covers one 16B f32 slot, 4 slabs ----
    const int srow = tid >> 4;        // 0..31
    const int sc16 = tid & 15;

    f32x4 acc[8][2] = {};             // [m-frag][n-frag]
    f32x4 sg[4];                      // staged f32 (reused per half-iteration)

    #define STAGE_LOAD(kc_)                                                   \
        do {                                                                  \
            _Pragma("unroll")                                                 \
            for (int it = 0; it < 4; ++it)                                    \
                sg[it] = *reinterpret_cast<const f32x4*>(                     \
                    x + (size_t)(m0 + it * 32 + srow) * K_DIM + (kc_) * KC + sc16 * 4); \
        } while (0)

    #define STAGE_WRITE(buf_)                                                 \
        do {                                                                  \
            _Pragma("unroll")                                                 \
            for (int it = 0; it < 4; ++it) {                                  \
                const int row = it * 32 + srow;                               \
                short4 p;                                                     \
                p.x = f2b(sg[it][0]); p.y = f2b(sg[it][1]);                   \
                p.z = f2b(sg[it][2]); p.w = f2b(sg[it][3]);                   \
                *reinterpret_cast<short4*>(smem + (buf_) * 16384 + row * 128  \
                    + ((sc16 * 8) ^ ((row & 7) << 4))) = p;                   \
            }                                                                 \
        } while (0)

    #define B_LOAD(c_)                                                        \
        do {                                                                  \
            _Pragma("unroll")                                                 \
            for (int s = 0; s < 2; ++s)                                       \
                _Pragma("unroll")                                             \
                for (int j = 0; j < 2; ++j)                                   \
                    bfr[s][j] = *reinterpret_cast<const bf16x8*>(             \
                        Wb + (size_t)(n0 + j * 16 + l16) * K_DIM + (c_) * KC  \
                           + s * 32 + g * 8);                                 \
        } while (0)

    #define COMPUTE(c_)                                                       \
        do {                                                                  \
            const int bufb = ((c_) & 3) * 16384;                              \
            __builtin_amdgcn_s_setprio(1);                                    \
            _Pragma("unroll")                                                 \
            for (int s = 0; s < 2; ++s) {                                     \
                _Pragma("unroll")                                             \
                for (int i = 0; i < 8; ++i) {                                 \
                    const int row = i * 16 + l16;                             \
                    bf16x8 av = *reinterpret_cast<const bf16x8*>(             \
                        smem + bufb + row * 128 +                             \
                        ((s * 64 + g * 16) ^ ((row & 7) << 4)));              \
                    _Pragma("unroll")                                         \
                    for (int j = 0; j < 2; ++j)                               \
                        acc[i][j] = __builtin_amdgcn_mfma_f32_16x16x32_bf16(  \
                            av, bfr[s][j], acc[i][j], 0, 0, 0);               \
                }                                                             \
            }                                                                 \
            __builtin_amdgcn_s_setprio(0);                                    \
        } while (0)

    // ---- prologue: stage chunks 0,1 into buffers 0,1 ----
    STAGE_LOAD(0);
    asm volatile("s_waitcnt vmcnt(0)" ::: "memory");
    STAGE_WRITE(0);
    STAGE_LOAD(1);
    asm volatile("s_waitcnt vmcnt(0)" ::: "memory");
    STAGE_WRITE(1);

    // ---- K loop: 8 chunks, TWO per barrier, 4-deep buffer rotation ----
    #pragma unroll
    for (int kk = 0; kk < NKC; kk += 2) {
        bf16x8 bfr[2][2];
        BAR();   // chunks kk,kk+1 visible; buffers (kk+2)&3,(kk+3)&3 free

        // --- chunk kk ---
        B_LOAD(kk);                          // oldest -> counted B-use wait
        __builtin_amdgcn_sched_barrier(0);
        if (kk + 2 < NKC) STAGE_LOAD(kk + 2);   // newest; fly over compute
        __builtin_amdgcn_sched_barrier(0);
        COMPUTE(kk);
        if (kk + 2 < NKC) {
            asm volatile("s_waitcnt vmcnt(0)" ::: "memory");  // free (R16)
            STAGE_WRITE((kk + 2) & 3);
        }

        // --- chunk kk+1 (same sub-schedule, registers reused) ---
        B_LOAD(kk + 1);
        __builtin_amdgcn_sched_barrier(0);
        if (kk + 3 < NKC) STAGE_LOAD(kk + 3);
        __builtin_amdgcn_sched_barrier(0);
        COMPUTE(kk + 1);
        if (kk + 3 < NKC) {
            asm volatile("s_waitcnt vmcnt(0)" ::: "memory");
            STAGE_WRITE((kk + 3) & 3);
        }
    }
    #undef STAGE_LOAD
    #undef STAGE_WRITE
    #undef B_LOAD
    #undef COMPUTE

    // ---- bias + tanh in regs ----
    // D layout: col = lane&15, row(within 16x16) = (lane>>4)*4 + r
    #pragma unroll
    for (int j = 0; j < 2; ++j) {
        const float bj = bias[n0 + j * 16 + l16];
        #pragma unroll
        for (int i = 0; i < 8; ++i)
            #pragma unroll
            for (int r = 0; r < 4; ++r)
                acc[i][j][r] = fast_tanh(acc[i][j][r] + bj);
    }

    // ---- in-register segmented product, per 64-row half h ----
    // Virtual 64-row group vb = bid*2 + h keeps partial/pass2 layout stable.
    #pragma unroll
    for (int h = 0; h < 2; ++h) {
        const int vb     = bid * 2 + h;
        const int myseg  = seg[m0 + h * 64 + lane];
        const int prevsg = (lane == 0) ? (myseg ^ 1) : seg[m0 + h * 64 + lane - 1];
        uint64_t m = __ballot(myseg != prevsg);              // run-start bits

        while (m) {
            const int start = (int)__builtin_ctzll(m);
            m &= m - 1;
            const int end = m ? (int)__builtin_ctzll(m) : 64;
            const int s   = __shfl(myseg, start);            // run's segment id

            float p[2] = {1.0f, 1.0f};
            #pragma unroll
            for (int i2 = 0; i2 < 4; ++i2)
                #pragma unroll
                for (int r = 0; r < 4; ++r) {
                    const int row = i2 * 16 + g * 4 + r;     // row within half
                    const bool in = (row >= start) && (row < end);
                    #pragma unroll
                    for (int j = 0; j < 2; ++j)
                        p[j] *= in ? acc[h * 4 + i2][j][r] : 1.0f;
                }
            #pragma unroll
            for (int j = 0; j < 2; ++j) {
                p[j] *= __shfl_xor(p[j], 16);
                p[j] *= __shfl_xor(p[j], 32);
            }
            if (g == 0) {
                #pragma unroll
                for (int j = 0; j < 2; ++j) {
                    const int col = n0 + j * 16 + l16;
                    if (start == 0)
                        partial[(size_t)(vb * 2 + 0) * N_RANK + col] = p[j];
                    else if (end == 64)
                        partial[(size_t)(vb * 2 + 1) * N_RANK + col] = p[j];
                    else
                        out[(size_t)s * N_RANK + col] = p[j]; // interior: exclusive
                }
            }
        }
    }
}

// Kernel 3 (pass 2): combine boundary partials over 64-row groups (b = vb).
// Group b owns boundary segment s iff s first appears in group b. Interior
// segments were stored by pass 1; empty segments stay 1.0.
__global__ void pass2_kernel(const int* __restrict__ seg,
                             const float* __restrict__ partial,
                             float* __restrict__ out) {
    const int b   = blockIdx.x;
    const int col = threadIdx.x;      // 0..255
    const int sF    = seg[b * 64];
    const int sL    = seg[b * 64 + 63];
    const int prevL = (b == 0) ? -1 : seg[b * 64 - 1];

    if (prevL < sF) {                 // b owns its first segment
        float p = partial[(size_t)(b * 2 + 0) * N_RANK + col];
        for (int b2 = b + 1; b2 < NB64 && seg[b2 * 64] == sF; ++b2)
            p *= partial[(size_t)(b2 * 2 + 0) * N_RANK + col];
        out[(size_t)sF * N_RANK + col] = p;
    }
    if (sL != sF) {                   // b always owns sL when sL != sF
        float p = partial[(size_t)(b * 2 + 1) * N_RANK + col];
        for (int b2 = b + 1; b2 < NB64 && seg[b2 * 64] == sL; ++b2)
            p *= partial[(size_t)(b2 * 2 + 0) * N_RANK + col];
        out[(size_t)sL * N_RANK + col] = p;
    }
}

extern "C" void kernel_launch(void* const* d_in, const int* in_sizes, int n_in,
                              void* d_out, int out_size, void* d_ws, size_t ws_size,
                              hipStream_t stream) {
    const float* x   = (const float*)d_in[0];
    const float* W   = (const float*)d_in[1];
    const float* b   = (const float*)d_in[2];
    const int*   seg = (const int*)d_in[3];
    float*       out = (float*)d_out;
    __hip_bfloat16* Wb = (__hip_bfloat16*)d_ws;                       // 256 KB
    float* partial = (float*)((char*)d_ws + (1 << 20));               // 4 MB @ +1MB

    prep_kernel<<<(NSEG * N_RANK) / 256, 256, 0, stream>>>(W, Wb, out);
    fused_kernel<<<NBLK, 512, 0, stream>>>(x, Wb, b, seg, out, partial);
    pass2_kernel<<<NB64, 256, 0, stream>>>(seg, partial, out);
}

// Round 25
// 77.245 us; speedup vs baseline: 3.7081x; 1.0137x over previous
//
#include <hip/hip_runtime.h>
#include <hip/hip_bf16.h>
#include <stdint.h>

// Problem constants (from reference)
#define M_TOTAL 131072
#define K_DIM   512
#define N_RANK  256
#define NSEG    1024
#define KC      64              // k-chunk staged in LDS (64 bf16 per row)
#define NKC     (K_DIM / KC)    // 8
#define BM      128             // rows per block
#define NBLK    (M_TOTAL / BM)  // 1024 fused blocks
#define NB64    (M_TOTAL / 64)  // 2048 virtual 64-row groups (pass2 granularity)

typedef __attribute__((ext_vector_type(8))) short bf16x8;
typedef __attribute__((ext_vector_type(4))) float f32x4;

// Raw barrier: lgkmcnt(0) makes my ds_writes visible, vmcnt NOT drained.
#define BAR() do { \
    asm volatile("s_waitcnt lgkmcnt(0)" ::: "memory"); \
    __builtin_amdgcn_s_barrier(); \
} while (0)

__device__ inline short f2b(float f) {
    __hip_bfloat16 h = __float2bfloat16(f);
    return __builtin_bit_cast(short, h);
}

// fast tanh: t = sign(z) * (1 - 2/(e^{2|z|}+1))
__device__ inline float fast_tanh(float z) {
    float e = __expf(2.0f * fabsf(z));
    return copysignf(1.0f - 2.0f / (e + 1.0f), z);
}

// Kernel 1: init out to 1.0 (segment_prod identity for empty segments)
//           + convert W to bf16 in ws
__global__ void prep_kernel(const float* __restrict__ W,
                            __hip_bfloat16* __restrict__ Wb,
                            float* __restrict__ out) {
    int i = blockIdx.x * 256 + threadIdx.x;
    out[i] = 1.0f;
    if (i < N_RANK * K_DIM) Wb[i] = __float2bfloat16(W[i]);
}

// Kernel 2 (pass 1): fused GEMM + bias + tanh + in-register segmented product.
//
// R25 = R22 + B_LOAD(kk) hoisted ABOVE the barrier. B is register-private
// (no LDS dep) and the VMEM queue is empty at that point (prior vmcnt(0)
// drained it), so the hoisted B flies across the rendezvous and the first
// MFMA's B-operand is already resident -- removes ~200cy exposed L2 latency
// per iteration at ZERO register cost (bfr live range extends only across
// the barrier). B_LOAD(kk+1) hoist would need a second bfr set (+16 regs >
// 128-cap): forbidden (spill wall measured 4x: R13/R14/R17/R23).
//
// Final structure pins (measured R1-R24):
//  - 8-wave col-slice, BM=128, KC=64: uniquely fits the (512,4) 128-reg cap.
//  - TWO chunks per barrier, 4-deep LDS rotation (R22 -3us): barriers 8->4.
//  - bf16 converted ONCE at stage-write (R12 -7.4us).
//  - B-loads oldest in VMEM queue -> counted B-use wait; G-loads newest ->
//    fly over compute (R9 -5us). Mid-chunk G-drain free (R16).
//  - setprio around MFMA kept (R19, free). De-phasing hurts L2 (R20).
//  - Epilogue: in-register segmented product (ballot-run-walk + shfl_xor,
//    R8); no atomics (two-pass partial combine, R7).
__launch_bounds__(512, 4)   // reg cap 128; spill canary = WRITE_SIZE balloon
__global__ void fused_kernel(const float* __restrict__ x,
                             const __hip_bfloat16* __restrict__ Wb,
                             const float* __restrict__ bias,
                             const int* __restrict__ seg,
                             float* __restrict__ out,
                             float* __restrict__ partial) {
    const int tid  = threadIdx.x;
    const int wave = tid >> 6;        // 0..7 = column-slice
    const int lane = tid & 63;
    const int l16  = lane & 15;
    const int g    = lane >> 4;       // 0..3 (k-group / row-group)
    const int bid  = blockIdx.x;
    const int m0   = bid * BM;
    const int n0   = wave * 32;

    // LDS: A quad-buffer, 4 x (128 rows x 128B bf16) = 64 KB.
    __shared__ alignas(16) char smem[65536];

    // ---- staging geometry: thread covers one 16B f32 slot, 4 slabs ----
    const int srow = tid >> 4;        // 0..31
    const int sc16 = tid & 15;

    f32x4 acc[8][2] = {};             // [m-frag][n-frag]
    f32x4 sg[4];                      // staged f32 (reused per half-iteration)

    #define STAGE_LOAD(kc_)                                                   \
        do {                                                                  \
            _Pragma("unroll")                                                 \
            for (int it = 0; it < 4; ++it)                                    \
                sg[it] = *reinterpret_cast<const f32x4*>(                     \
                    x + (size_t)(m0 + it * 32 + srow) * K_DIM + (kc_) * KC + sc16 * 4); \
        } while (0)

    #define STAGE_WRITE(buf_)                                                 \
        do {                                                                  \
            _Pragma("unroll")                                                 \
            for (int it = 0; it < 4; ++it) {                                  \
                const int row = it * 32 + srow;                               \
                short4 p;                                                     \
                p.x = f2b(sg[it][0]); p.y = f2b(sg[it][1]);                   \
                p.z = f2b(sg[it][2]); p.w = f2b(sg[it][3]);                   \
                *reinterpret_cast<short4*>(smem + (buf_) * 16384 + row * 128  \
                    + ((sc16 * 8) ^ ((row & 7) << 4))) = p;                   \
            }                                                                 \
        } while (0)

    #define B_LOAD(c_)                                                        \
        do {                                                                  \
            _Pragma("unroll")                                                 \
            for (int s = 0; s < 2; ++s)                                       \
                _Pragma("unroll")                                             \
                for (int j = 0; j < 2; ++j)                                   \
                    bfr[s][j] = *reinterpret_cast<const bf16x8*>(             \
                        Wb + (size_t)(n0 + j * 16 + l16) * K_DIM + (c_) * KC  \
                           + s * 32 + g * 8);                                 \
        } while (0)

    #define COMPUTE(c_)                                                       \
        do {                                                                  \
            const int bufb = ((c_) & 3) * 16384;                              \
            __builtin_amdgcn_s_setprio(1);                                    \
            _Pragma("unroll")                                                 \
            for (int s = 0; s < 2; ++s) {                                     \
                _Pragma("unroll")                                             \
                for (int i = 0; i < 8; ++i) {                                 \
                    const int row = i * 16 + l16;                             \
                    bf16x8 av = *reinterpret_cast<const bf16x8*>(             \
                        smem + bufb + row * 128 +                             \
                        ((s * 64 + g * 16) ^ ((row & 7) << 4)));              \
                    _Pragma("unroll")                                         \
                    for (int j = 0; j < 2; ++j)                               \
                        acc[i][j] = __builtin_amdgcn_mfma_f32_16x16x32_bf16(  \
                            av, bfr[s][j], acc[i][j], 0, 0, 0);               \
                }                                                             \
            }                                                                 \
            __builtin_amdgcn_s_setprio(0);                                    \
        } while (0)

    // ---- prologue: stage chunks 0,1 into buffers 0,1 ----
    STAGE_LOAD(0);
    asm volatile("s_waitcnt vmcnt(0)" ::: "memory");
    STAGE_WRITE(0);
    STAGE_LOAD(1);
    asm volatile("s_waitcnt vmcnt(0)" ::: "memory");
    STAGE_WRITE(1);

    // ---- K loop: 8 chunks, TWO per barrier, 4-deep buffer rotation ----
    #pragma unroll
    for (int kk = 0; kk < NKC; kk += 2) {
        bf16x8 bfr[2][2];

        // B for chunk kk issued BEFORE the barrier (R25): queue is empty
        // here (prior vmcnt(0) drained), B flies across the rendezvous.
        B_LOAD(kk);
        __builtin_amdgcn_sched_barrier(0);   // pin: B(kk) above the barrier

        BAR();   // chunks kk,kk+1 visible; buffers (kk+2)&3,(kk+3)&3 free

        // --- chunk kk ---
        if (kk + 2 < NKC) STAGE_LOAD(kk + 2);   // newest; fly over compute
        __builtin_amdgcn_sched_barrier(0);
        COMPUTE(kk);
        if (kk + 2 < NKC) {
            asm volatile("s_waitcnt vmcnt(0)" ::: "memory");  // free (R16)
            STAGE_WRITE((kk + 2) & 3);
        }

        // --- chunk kk+1 (same sub-schedule, registers reused) ---
        B_LOAD(kk + 1);
        __builtin_amdgcn_sched_barrier(0);
        if (kk + 3 < NKC) STAGE_LOAD(kk + 3);
        __builtin_amdgcn_sched_barrier(0);
        COMPUTE(kk + 1);
        if (kk + 3 < NKC) {
            asm volatile("s_waitcnt vmcnt(0)" ::: "memory");
            STAGE_WRITE((kk + 3) & 3);
        }
    }
    #undef STAGE_LOAD
    #undef STAGE_WRITE
    #undef B_LOAD
    #undef COMPUTE

    // ---- bias + tanh in regs ----
    // D layout: col = lane&15, row(within 16x16) = (lane>>4)*4 + r
    #pragma unroll
    for (int j = 0; j < 2; ++j) {
        const float bj = bias[n0 + j * 16 + l16];
        #pragma unroll
        for (int i = 0; i < 8; ++i)
            #pragma unroll
            for (int r = 0; r < 4; ++r)
                acc[i][j][r] = fast_tanh(acc[i][j][r] + bj);
    }

    // ---- in-register segmented product, per 64-row half h ----
    // Virtual 64-row group vb = bid*2 + h keeps partial/pass2 layout stable.
    #pragma unroll
    for (int h = 0; h < 2; ++h) {
        const int vb     = bid * 2 + h;
        const int myseg  = seg[m0 + h * 64 + lane];
        const int prevsg = (lane == 0) ? (myseg ^ 1) : seg[m0 + h * 64 + lane - 1];
        uint64_t m = __ballot(myseg != prevsg);              // run-start bits

        while (m) {
            const int start = (int)__builtin_ctzll(m);
            m &= m - 1;
            const int end = m ? (int)__builtin_ctzll(m) : 64;
            const int s   = __shfl(myseg, start);            // run's segment id

            float p[2] = {1.0f, 1.0f};
            #pragma unroll
            for (int i2 = 0; i2 < 4; ++i2)
                #pragma unroll
                for (int r = 0; r < 4; ++r) {
                    const int row = i2 * 16 + g * 4 + r;     // row within half
                    const bool in = (row >= start) && (row < end);
                    #pragma unroll
                    for (int j = 0; j < 2; ++j)
                        p[j] *= in ? acc[h * 4 + i2][j][r] : 1.0f;
                }
            #pragma unroll
            for (int j = 0; j < 2; ++j) {
                p[j] *= __shfl_xor(p[j], 16);
                p[j] *= __shfl_xor(p[j], 32);
            }
            if (g == 0) {
                #pragma unroll
                for (int j = 0; j < 2; ++j) {
                    const int col = n0 + j * 16 + l16;
                    if (start == 0)
                        partial[(size_t)(vb * 2 + 0) * N_RANK + col] = p[j];
                    else if (end == 64)
                        partial[(size_t)(vb * 2 + 1) * N_RANK + col] = p[j];
                    else
                        out[(size_t)s * N_RANK + col] = p[j]; // interior: exclusive
                }
            }
        }
    }
}

// Kernel 3 (pass 2): combine boundary partials over 64-row groups (b = vb).
// Group b owns boundary segment s iff s first appears in group b. Interior
// segments were stored by pass 1; empty segments stay 1.0.
__global__ void pass2_kernel(const int* __restrict__ seg,
                             const float* __restrict__ partial,
                             float* __restrict__ out) {
    const int b   = blockIdx.x;
    const int col = threadIdx.x;      // 0..255
    const int sF    = seg[b * 64];
    const int sL    = seg[b * 64 + 63];
    const int prevL = (b == 0) ? -1 : seg[b * 64 - 1];

    if (prevL < sF) {                 // b owns its first segment
        float p = partial[(size_t)(b * 2 + 0) * N_RANK + col];
        for (int b2 = b + 1; b2 < NB64 && seg[b2 * 64] == sF; ++b2)
            p *= partial[(size_t)(b2 * 2 + 0) * N_RANK + col];
        out[(size_t)sF * N_RANK + col] = p;
    }
    if (sL != sF) {                   // b always owns sL when sL != sF
        float p = partial[(size_t)(b * 2 + 1) * N_RANK + col];
        for (int b2 = b + 1; b2 < NB64 && seg[b2 * 64] == sL; ++b2)
            p *= partial[(size_t)(b2 * 2 + 0) * N_RANK + col];
        out[(size_t)sL * N_RANK + col] = p;
    }
}

extern "C" void kernel_launch(void* const* d_in, const int* in_sizes, int n_in,
                              void* d_out, int out_size, void* d_ws, size_t ws_size,
                              hipStream_t stream) {
    const float* x   = (const float*)d_in[0];
    const float* W   = (const float*)d_in[1];
    const float* b   = (const float*)d_in[2];
    const int*   seg = (const int*)d_in[3];
    float*       out = (float*)d_out;
    __hip_bfloat16* Wb = (__hip_bfloat16*)d_ws;                       // 256 KB
    float* partial = (float*)((char*)d_ws + (1 << 20));               // 4 MB @ +1MB

    prep_kernel<<<(NSEG * N_RANK) / 256, 256, 0, stream>>>(W, Wb, out);
    fused_kernel<<<NBLK, 512, 0, stream>>>(x, Wb, b, seg, out, partial);
    pass2_kernel<<<NB64, 256, 0, stream>>>(seg, partial, out);
}